// Round 20
// baseline (115.623 us; speedup 1.0000x reference)
//
#include <hip/hip_runtime.h>

#define DIM 256
#define NA 16
#define NE 4
#define KTOT 288   // 16 atoms + 256 latent + 16 zero pad (9 chunks of 32)

typedef __attribute__((ext_vector_type(8))) short short8;
typedef __attribute__((ext_vector_type(4))) float f32x4;

static __device__ __forceinline__ ushort f2bf(float f) {
  union { float f; unsigned int u; } v; v.f = f;
  unsigned int r = (v.u + 0x7FFFu + ((v.u >> 16) & 1u)) >> 16;
  return (ushort)r;
}

static __device__ __forceinline__ float bf2f(ushort s) {
  union { unsigned int u; float f; } v; v.u = ((unsigned int)s) << 16;
  return v.f;
}

static __device__ __forceinline__ unsigned cvtpk(float lo, float hi) {
  unsigned r;
  asm("v_cvt_pk_bf16_f32 %0, %1, %2" : "=v"(r) : "v"(lo), "v"(hi));
  return r;
}

// fragment-major index (ushort units): subtile = 16 rows x 32 cols = 1KB,
// laid out [row-block rb][k-chunk kk][oct][r15][e]:
//   idx = ((rb*9 + kk)*4 + oct)*128 + r15*8 + e
static __device__ __forceinline__ int fragIdx(int row, int c) {
  return (((row >> 4)*9 + (c >> 5))*4 + ((c >> 3) & 3))*128 + (row & 15)*8 + (c & 7);
}

// ---------------- prep 1: h = relu(latent@W1+b1)@W2+b2 ; Gf = frag-major [atoms|h|0] bf16
__global__ __launch_bounds__(256) void prep_h_kernel(
    const float* __restrict__ latent, const float* __restrict__ atoms,
    const float* __restrict__ W1, const float* __restrict__ b1,
    const float* __restrict__ W2, const float* __restrict__ b2,
    ushort* __restrict__ Gf) {
  __shared__ float lat[8][DIM];
  __shared__ float t1[8][DIM];
  const int b = blockIdx.x >> 5, i0 = (blockIdx.x & 31) * 8;
  const int k = threadIdx.x;
  #pragma unroll
  for (int r = 0; r < 8; ++r) lat[r][k] = latent[(b*256 + i0 + r) * DIM + k];
  __syncthreads();
  float acc[8];
  #pragma unroll
  for (int r = 0; r < 8; ++r) acc[r] = b1[k];
  for (int c = 0; c < DIM; c += 4) {
    float w0 = W1[(c+0)*DIM + k], w1 = W1[(c+1)*DIM + k];
    float w2 = W1[(c+2)*DIM + k], w3 = W1[(c+3)*DIM + k];
    #pragma unroll
    for (int r = 0; r < 8; ++r) {
      const float4 l4 = *reinterpret_cast<const float4*>(&lat[r][c]);
      acc[r] += l4.x*w0 + l4.y*w1 + l4.z*w2 + l4.w*w3;
    }
  }
  #pragma unroll
  for (int r = 0; r < 8; ++r) t1[r][k] = fmaxf(acc[r], 0.f);
  __syncthreads();
  #pragma unroll
  for (int r = 0; r < 8; ++r) acc[r] = b2[k];
  for (int c = 0; c < DIM; c += 4) {
    float w0 = W2[(c+0)*DIM + k], w1 = W2[(c+1)*DIM + k];
    float w2 = W2[(c+2)*DIM + k], w3 = W2[(c+3)*DIM + k];
    #pragma unroll
    for (int r = 0; r < 8; ++r) {
      const float4 l4 = *reinterpret_cast<const float4*>(&t1[r][c]);
      acc[r] += l4.x*w0 + l4.y*w1 + l4.z*w2 + l4.w*w3;
    }
  }
  #pragma unroll
  for (int r = 0; r < 8; ++r) {
    int row = b*256 + i0 + r;
    Gf[fragIdx(row, NA + k)] = f2bf(acc[r]);
  }
  if (k < NA) {
    #pragma unroll
    for (int r = 0; r < 8; ++r) {
      int row = b*256 + i0 + r;
      Gf[fragIdx(row, k)] = f2bf(atoms[row*NA + k]);
      Gf[fragIdx(row, 272 + k)] = 0;
    }
  }
}

// ---------------- prep 2: W3Tf frag-major: value(n,c) = bf16(W3[1+c][n]), pad 0
__global__ __launch_bounds__(256) void prep_w3t_kernel(
    const float* __restrict__ W3, ushort* __restrict__ W3Tf) {
  const int n = blockIdx.x, c = threadIdx.x;
  W3Tf[fragIdx(n, c)] = (c < 272) ? f2bf(W3[(1+c)*DIM + n]) : (ushort)0;
  if (c < 32) {
    int c2 = 256 + c;
    W3Tf[fragIdx(n, c2)] = (c2 < 272) ? f2bf(W3[(1+c2)*DIM + n]) : (ushort)0;
  }
}

// ---------------- main: one WG per (b, it<=jt, i-quarter) = 4352 WGs x 256 thr.
// COOPERATIVE y-BUILD: the 64x288 pair-product table is built ONCE per WG into
// LDS (it is wave-invariant; R19 rebuilt it 4x, once per wave). K-loop is then
// barrier-free and instruction-lean: 4 afr L2-loads + 4 bb ds_reads + 16 MFMA
// per kk. Stride-5 octet padding makes y reads AND writes perfect 2-way.
// 4-wave WG + waves_per_eu(3,3) -> 3 independent WGs per SIMD.
__global__ __attribute__((amdgpu_flat_work_group_size(256,256), amdgpu_waves_per_eu(3,3)))
void edge_main_kernel(
    const float* __restrict__ positions,
    const float* __restrict__ W3, const float* __restrict__ b3,
    const float* __restrict__ W4, const float* __restrict__ b4,
    const ushort* __restrict__ Gf, const ushort* __restrict__ W3Tf,
    float* __restrict__ out) {
  __shared__ ushort y_lds[9*64*5*8];     // y[kk][pair][slot5] 8-elem octets, 45KB
  __shared__ float partial[4][64][4];    // 4KB
  __shared__ float dist_lds[64];

  const int bid = blockIdx.x;
  const int b = bid / 544;               // 136 tiles * 4 quarters per b
  int rem = bid - b*544;
  const int qq4 = rem & 3;               // i-quarter: rows [qq4*4, qq4*4+4)
  int q = rem >> 2;
  int it = 0;
  while (q >= 16 - it) { q -= 16 - it; ++it; }
  const int jt = it + q;
  const int i0 = b*256 + it*16, j0 = b*256 + jt*16;
  const int rbi = i0 >> 4, rbj = j0 >> 4;

  const int tid = threadIdx.x;
  const int lane = tid & 63, w = tid >> 6;   // w = n-group (ntiles w*4..+4)
  const int c15 = lane & 15, hi = lane >> 4;

  // ---- cooperative y-build: thread (p = tid>>2, oct = tid&3) computes
  // y[kk][p][oct] = bf16(gi[qq4*4 + p>>4][kk*32+oct*8..+8] * gj[p&15][same])
  {
    const int p = tid >> 2, oct = tid & 3;
    const int ri = qq4*4 + (p >> 4);         // i-row within block (0..15)
    const int rj = p & 15;                   // j-row within block
    const ushort* giB = &Gf[(size_t)(rbi*9)*512 + oct*128 + ri*8];
    const ushort* gjB = &Gf[(size_t)(rbj*9)*512 + oct*128 + rj*8];
    #pragma unroll
    for (int kk = 0; kk < 9; ++kk) {
      union { ushort us[8]; short8 s8; } gi, gj;
      gi.s8 = *reinterpret_cast<const short8*>(giB + kk*512);
      gj.s8 = *reinterpret_cast<const short8*>(gjB + kk*512);
      union { unsigned uu[4]; short8 s8; } pk;
      pk.uu[0] = cvtpk(bf2f(gi.us[0])*bf2f(gj.us[0]), bf2f(gi.us[1])*bf2f(gj.us[1]));
      pk.uu[1] = cvtpk(bf2f(gi.us[2])*bf2f(gj.us[2]), bf2f(gi.us[3])*bf2f(gj.us[3]));
      pk.uu[2] = cvtpk(bf2f(gi.us[4])*bf2f(gj.us[4]), bf2f(gi.us[5])*bf2f(gj.us[5]));
      pk.uu[3] = cvtpk(bf2f(gi.us[6])*bf2f(gj.us[6]), bf2f(gi.us[7])*bf2f(gj.us[7]));
      *reinterpret_cast<short8*>(&y_lds[((kk*64 + p)*5 + oct)*8]) = pk.s8;
    }
  }
  if (tid < 64) {
    int pi = tid >> 4, pj = tid & 15;
    const float* pa = &positions[(i0 + qq4*4 + pi)*3];
    const float* pb = &positions[(j0 + pj)*3];
    float dx = pa[0]-pb[0], dy = pa[1]-pb[1], dz = pa[2]-pb[2];
    float d2 = dx*dx + dy*dy + dz*dz;
    dist_lds[tid] = d2 > 0.f ? sqrtf(d2) : 0.f;
  }

  f32x4 acc[4][4];
  #pragma unroll
  for (int at = 0; at < 4; ++at)
    #pragma unroll
    for (int bt = 0; bt < 4; ++bt) { acc[at][bt].x=0.f; acc[at][bt].y=0.f; acc[at][bt].z=0.f; acc[at][bt].w=0.f; }

  __syncthreads();   // y + dist visible; no more barriers until epilogue

  #pragma unroll
  for (int kk = 0; kk < 9; ++kk) {
    // B-fragments: single ds_read_b128 each (2-way bank pattern, free)
    short8 bbv[4];
    #pragma unroll
    for (int bt = 0; bt < 4; ++bt)
      bbv[bt] = *reinterpret_cast<const short8*>(
          &y_lds[((kk*64 + bt*16 + c15)*5 + hi)*8]);
    // A-fragments from W3Tf (L2), one at a time (register-lean)
    #pragma unroll
    for (int at = 0; at < 4; ++at) {
      short8 af = *reinterpret_cast<const short8*>(
          &W3Tf[((w*4 + at)*9 + kk)*512 + lane*8]);
      acc[at][0] = __builtin_amdgcn_mfma_f32_16x16x32_bf16(af, bbv[0], acc[at][0], 0, 0, 0);
      acc[at][1] = __builtin_amdgcn_mfma_f32_16x16x32_bf16(af, bbv[1], acc[at][1], 0, 0, 0);
      acc[at][2] = __builtin_amdgcn_mfma_f32_16x16x32_bf16(af, bbv[2], acc[at][2], 0, 0, 0);
      acc[at][3] = __builtin_amdgcn_mfma_f32_16x16x32_bf16(af, bbv[3], acc[at][3], 0, 0, 0);
    }
  }

  __builtin_amdgcn_sched_barrier(0);   // keep epilogue loads out of K-loop region

  // ---- epilogue: per-at constant loading caps register pressure
  float4 pe[4];
  #pragma unroll
  for (int bt = 0; bt < 4; ++bt) { pe[bt].x=0.f; pe[bt].y=0.f; pe[bt].z=0.f; pe[bt].w=0.f; }
  #pragma unroll
  for (int at = 0; at < 4; ++at) {
    float b3v[4], w30v[4]; float4 w4v[4];
    #pragma unroll
    for (int r = 0; r < 4; ++r) {
      int n = (w*4 + at)*16 + hi*4 + r;
      b3v[r]  = b3[n];
      w30v[r] = W3[n];                 // W3 row 0 = dist weights
      w4v[r]  = *reinterpret_cast<const float4*>(&W4[n*4]);
    }
    #pragma unroll
    for (int bt = 0; bt < 4; ++bt) {
      float d = dist_lds[bt*16 + c15];
      #pragma unroll
      for (int r = 0; r < 4; ++r) {
        float z  = acc[at][bt][r] + d*w30v[r] + b3v[r];
        float rz = fmaxf(z, 0.f);
        pe[bt].x += rz*w4v[r].x; pe[bt].y += rz*w4v[r].y;
        pe[bt].z += rz*w4v[r].z; pe[bt].w += rz*w4v[r].w;
      }
    }
  }
  #pragma unroll
  for (int bt = 0; bt < 4; ++bt) {
    int pair = bt*16 + c15;
    float4 p = pe[bt];
    p.x += __shfl_xor(p.x, 16); p.y += __shfl_xor(p.y, 16);
    p.z += __shfl_xor(p.z, 16); p.w += __shfl_xor(p.w, 16);
    p.x += __shfl_xor(p.x, 32); p.y += __shfl_xor(p.y, 32);
    p.z += __shfl_xor(p.z, 32); p.w += __shfl_xor(p.w, 32);
    if (hi == 0) *reinterpret_cast<float4*>(&partial[w][pair][0]) = p;
  }
  __syncthreads();
  if (tid < 64) {
    int pair = tid;
    float4 v;
    v.x = partial[0][pair][0] + partial[1][pair][0] + partial[2][pair][0] + partial[3][pair][0];
    v.y = partial[0][pair][1] + partial[1][pair][1] + partial[2][pair][1] + partial[3][pair][1];
    v.z = partial[0][pair][2] + partial[1][pair][2] + partial[2][pair][2] + partial[3][pair][2];
    v.w = partial[0][pair][3] + partial[1][pair][3] + partial[2][pair][3] + partial[3][pair][3];
    const float4 bv = *reinterpret_cast<const float4*>(b4);
    v.x += bv.x; v.y += bv.y; v.z += bv.z; v.w += bv.w;
    int il = it*16 + qq4*4 + (pair >> 4);   // local i row
    int jl = jt*16 + (pair & 15);           // local j row
    *reinterpret_cast<float4*>(&out[(((size_t)b*256 + il)*256 + jl)*NE]) = v;
    if (it != jt)
      *reinterpret_cast<float4*>(&out[(((size_t)b*256 + jl)*256 + il)*NE]) = v;
  }
}

extern "C" void kernel_launch(void* const* d_in, const int* in_sizes, int n_in,
                              void* d_out, int out_size, void* d_ws, size_t ws_size,
                              hipStream_t stream) {
  const float* latent    = (const float*)d_in[0];
  const float* positions = (const float*)d_in[1];
  const float* atoms     = (const float*)d_in[2];
  const float* W1 = (const float*)d_in[3];
  const float* b1 = (const float*)d_in[4];
  const float* W2 = (const float*)d_in[5];
  const float* b2 = (const float*)d_in[6];
  const float* W3 = (const float*)d_in[7];
  const float* b3 = (const float*)d_in[8];
  const float* W4 = (const float*)d_in[9];
  const float* b4 = (const float*)d_in[10];
  float* out = (float*)d_out;

  char* ws = (char*)d_ws;
  ushort* Gf_ws   = (ushort*)ws;                        // 8*256*288*2 = 1,179,648 B
  ushort* W3Tf_ws = (ushort*)(ws + 1179648);            // 256*288*2   =   147,456 B

  hipLaunchKernelGGL(prep_h_kernel, dim3(256), dim3(256), 0, stream,
                     latent, atoms, W1, b1, W2, b2, Gf_ws);
  hipLaunchKernelGGL(prep_w3t_kernel, dim3(256), dim3(256), 0, stream, W3, W3Tf_ws);
  hipLaunchKernelGGL(edge_main_kernel, dim3(4352), dim3(256), 0, stream,
                     positions, W3, b3, W4, b4, Gf_ws, W3Tf_ws, out);
}

// Round 21
// 115.411 us; speedup vs baseline: 1.0018x; 1.0018x over previous
//
#include <hip/hip_runtime.h>

#define DIM 256
#define NA 16
#define NE 4
#define KTOT 288   // 16 atoms + 256 latent + 16 zero pad (9 chunks of 32)

typedef __attribute__((ext_vector_type(8))) short short8;
typedef __attribute__((ext_vector_type(4))) float f32x4;

static __device__ __forceinline__ ushort f2bf(float f) {
  union { float f; unsigned int u; } v; v.f = f;
  unsigned int r = (v.u + 0x7FFFu + ((v.u >> 16) & 1u)) >> 16;
  return (ushort)r;
}

static __device__ __forceinline__ float bf2f(ushort s) {
  union { unsigned int u; float f; } v; v.u = ((unsigned int)s) << 16;
  return v.f;
}

static __device__ __forceinline__ unsigned cvtpk(float lo, float hi) {
  unsigned r;
  asm("v_cvt_pk_bf16_f32 %0, %1, %2" : "=v"(r) : "v"(lo), "v"(hi));
  return r;
}

// fragment-major index (ushort units): subtile = 16 rows x 32 cols = 1KB,
// laid out [row-block rb][k-chunk kk][oct][r15][e]:
//   idx = ((rb*9 + kk)*4 + oct)*128 + r15*8 + e
static __device__ __forceinline__ int fragIdx(int row, int c) {
  return (((row >> 4)*9 + (c >> 5))*4 + ((c >> 3) & 3))*128 + (row & 15)*8 + (c & 7);
}

// ---------------- prep 1: h = relu(latent@W1+b1)@W2+b2 ; Gf = frag-major [atoms|h|0] bf16
__global__ __launch_bounds__(256) void prep_h_kernel(
    const float* __restrict__ latent, const float* __restrict__ atoms,
    const float* __restrict__ W1, const float* __restrict__ b1,
    const float* __restrict__ W2, const float* __restrict__ b2,
    ushort* __restrict__ Gf) {
  __shared__ float lat[8][DIM];
  __shared__ float t1[8][DIM];
  const int b = blockIdx.x >> 5, i0 = (blockIdx.x & 31) * 8;
  const int k = threadIdx.x;
  #pragma unroll
  for (int r = 0; r < 8; ++r) lat[r][k] = latent[(b*256 + i0 + r) * DIM + k];
  __syncthreads();
  float acc[8];
  #pragma unroll
  for (int r = 0; r < 8; ++r) acc[r] = b1[k];
  for (int c = 0; c < DIM; c += 4) {
    float w0 = W1[(c+0)*DIM + k], w1 = W1[(c+1)*DIM + k];
    float w2 = W1[(c+2)*DIM + k], w3 = W1[(c+3)*DIM + k];
    #pragma unroll
    for (int r = 0; r < 8; ++r) {
      const float4 l4 = *reinterpret_cast<const float4*>(&lat[r][c]);
      acc[r] += l4.x*w0 + l4.y*w1 + l4.z*w2 + l4.w*w3;
    }
  }
  #pragma unroll
  for (int r = 0; r < 8; ++r) t1[r][k] = fmaxf(acc[r], 0.f);
  __syncthreads();
  #pragma unroll
  for (int r = 0; r < 8; ++r) acc[r] = b2[k];
  for (int c = 0; c < DIM; c += 4) {
    float w0 = W2[(c+0)*DIM + k], w1 = W2[(c+1)*DIM + k];
    float w2 = W2[(c+2)*DIM + k], w3 = W2[(c+3)*DIM + k];
    #pragma unroll
    for (int r = 0; r < 8; ++r) {
      const float4 l4 = *reinterpret_cast<const float4*>(&t1[r][c]);
      acc[r] += l4.x*w0 + l4.y*w1 + l4.z*w2 + l4.w*w3;
    }
  }
  #pragma unroll
  for (int r = 0; r < 8; ++r) {
    int row = b*256 + i0 + r;
    Gf[fragIdx(row, NA + k)] = f2bf(acc[r]);
  }
  if (k < NA) {
    #pragma unroll
    for (int r = 0; r < 8; ++r) {
      int row = b*256 + i0 + r;
      Gf[fragIdx(row, k)] = f2bf(atoms[row*NA + k]);
      Gf[fragIdx(row, 272 + k)] = 0;
    }
  }
}

// ---------------- prep 2: W3Tf frag-major: value(n,c) = bf16(W3[1+c][n]), pad 0
__global__ __launch_bounds__(256) void prep_w3t_kernel(
    const float* __restrict__ W3, ushort* __restrict__ W3Tf) {
  const int n = blockIdx.x, c = threadIdx.x;
  W3Tf[fragIdx(n, c)] = (c < 272) ? f2bf(W3[(1+c)*DIM + n]) : (ushort)0;
  if (c < 32) {
    int c2 = 256 + c;
    W3Tf[fragIdx(n, c2)] = (c2 < 272) ? f2bf(W3[(1+c2)*DIM + n]) : (ushort)0;
  }
}

// ---------------- main: one WG per (b, it<=jt, i-quarter) = 4352 WGs x 256 thr.
// Cooperative y-build (once per WG) + barrier-free K-loop with EXPLICIT 1-deep
// SOFTWARE PIPELINE: kk+1's afr (L2) and bbv (LDS) are prefetched into
// registers before kk's MFMA cluster, so load latency hides under MFMA.
// (R20 lesson: the lean loop alone is latency-exposed; R19's VALU was cover.)
__global__ __attribute__((amdgpu_flat_work_group_size(256,256), amdgpu_waves_per_eu(3,3)))
void edge_main_kernel(
    const float* __restrict__ positions,
    const float* __restrict__ W3, const float* __restrict__ b3,
    const float* __restrict__ W4, const float* __restrict__ b4,
    const ushort* __restrict__ Gf, const ushort* __restrict__ W3Tf,
    float* __restrict__ out) {
  __shared__ ushort y_lds[9*64*5*8];     // y[kk][pair][slot5] 8-elem octets, 45KB
  __shared__ float partial[4][64][4];    // 4KB
  __shared__ float dist_lds[64];

  const int bid = blockIdx.x;
  const int b = bid / 544;               // 136 tiles * 4 quarters per b
  int rem = bid - b*544;
  const int qq4 = rem & 3;               // i-quarter: rows [qq4*4, qq4*4+4)
  int q = rem >> 2;
  int it = 0;
  while (q >= 16 - it) { q -= 16 - it; ++it; }
  const int jt = it + q;
  const int i0 = b*256 + it*16, j0 = b*256 + jt*16;
  const int rbi = i0 >> 4, rbj = j0 >> 4;

  const int tid = threadIdx.x;
  const int lane = tid & 63, w = tid >> 6;   // w = n-group (ntiles w*4..+4)
  const int c15 = lane & 15, hi = lane >> 4;

  // ---- cooperative y-build: thread (p = tid>>2, oct = tid&3) computes
  // y[kk][p][oct] = bf16(gi[qq4*4 + p>>4][kk*32+oct*8..+8] * gj[p&15][same])
  {
    const int p = tid >> 2, oct = tid & 3;
    const int ri = qq4*4 + (p >> 4);         // i-row within block (0..15)
    const int rj = p & 15;                   // j-row within block
    const ushort* giB = &Gf[(size_t)(rbi*9)*512 + oct*128 + ri*8];
    const ushort* gjB = &Gf[(size_t)(rbj*9)*512 + oct*128 + rj*8];
    #pragma unroll
    for (int kk = 0; kk < 9; ++kk) {
      union { ushort us[8]; short8 s8; } gi, gj;
      gi.s8 = *reinterpret_cast<const short8*>(giB + kk*512);
      gj.s8 = *reinterpret_cast<const short8*>(gjB + kk*512);
      union { unsigned uu[4]; short8 s8; } pk;
      pk.uu[0] = cvtpk(bf2f(gi.us[0])*bf2f(gj.us[0]), bf2f(gi.us[1])*bf2f(gj.us[1]));
      pk.uu[1] = cvtpk(bf2f(gi.us[2])*bf2f(gj.us[2]), bf2f(gi.us[3])*bf2f(gj.us[3]));
      pk.uu[2] = cvtpk(bf2f(gi.us[4])*bf2f(gj.us[4]), bf2f(gi.us[5])*bf2f(gj.us[5]));
      pk.uu[3] = cvtpk(bf2f(gi.us[6])*bf2f(gj.us[6]), bf2f(gi.us[7])*bf2f(gj.us[7]));
      *reinterpret_cast<short8*>(&y_lds[((kk*64 + p)*5 + oct)*8]) = pk.s8;
    }
  }
  if (tid < 64) {
    int pi = tid >> 4, pj = tid & 15;
    const float* pa = &positions[(i0 + qq4*4 + pi)*3];
    const float* pb = &positions[(j0 + pj)*3];
    float dx = pa[0]-pb[0], dy = pa[1]-pb[1], dz = pa[2]-pb[2];
    float d2 = dx*dx + dy*dy + dz*dz;
    dist_lds[tid] = d2 > 0.f ? sqrtf(d2) : 0.f;
  }

  f32x4 acc[4][4];
  #pragma unroll
  for (int at = 0; at < 4; ++at)
    #pragma unroll
    for (int bt = 0; bt < 4; ++bt) { acc[at][bt].x=0.f; acc[at][bt].y=0.f; acc[at][bt].z=0.f; acc[at][bt].w=0.f; }

  __syncthreads();   // y + dist visible; no more barriers until epilogue

  // ---- software-pipelined K-loop (1-deep rotate registers, static indices)
  short8 afc[4], bbc[4];
  #pragma unroll
  for (int at = 0; at < 4; ++at)
    afc[at] = *reinterpret_cast<const short8*>(&W3Tf[((w*4 + at)*9 + 0)*512 + lane*8]);
  #pragma unroll
  for (int bt = 0; bt < 4; ++bt)
    bbc[bt] = *reinterpret_cast<const short8*>(&y_lds[((0*64 + bt*16 + c15)*5 + hi)*8]);

  #pragma unroll
  for (int kk = 0; kk < 9; ++kk) {
    short8 afn[4], bbn[4];
    if (kk < 8) {
      #pragma unroll
      for (int bt = 0; bt < 4; ++bt)
        bbn[bt] = *reinterpret_cast<const short8*>(
            &y_lds[(((kk+1)*64 + bt*16 + c15)*5 + hi)*8]);
      #pragma unroll
      for (int at = 0; at < 4; ++at)
        afn[at] = *reinterpret_cast<const short8*>(
            &W3Tf[((w*4 + at)*9 + (kk+1))*512 + lane*8]);
    }
    #pragma unroll
    for (int at = 0; at < 4; ++at) {
      acc[at][0] = __builtin_amdgcn_mfma_f32_16x16x32_bf16(afc[at], bbc[0], acc[at][0], 0, 0, 0);
      acc[at][1] = __builtin_amdgcn_mfma_f32_16x16x32_bf16(afc[at], bbc[1], acc[at][1], 0, 0, 0);
      acc[at][2] = __builtin_amdgcn_mfma_f32_16x16x32_bf16(afc[at], bbc[2], acc[at][2], 0, 0, 0);
      acc[at][3] = __builtin_amdgcn_mfma_f32_16x16x32_bf16(afc[at], bbc[3], acc[at][3], 0, 0, 0);
    }
    if (kk < 8) {
      #pragma unroll
      for (int t = 0; t < 4; ++t) { afc[t] = afn[t]; bbc[t] = bbn[t]; }
    }
  }

  __builtin_amdgcn_sched_barrier(0);   // keep epilogue loads out of K-loop region

  // ---- epilogue: per-at constant loading caps register pressure
  float4 pe[4];
  #pragma unroll
  for (int bt = 0; bt < 4; ++bt) { pe[bt].x=0.f; pe[bt].y=0.f; pe[bt].z=0.f; pe[bt].w=0.f; }
  #pragma unroll
  for (int at = 0; at < 4; ++at) {
    float b3v[4], w30v[4]; float4 w4v[4];
    #pragma unroll
    for (int r = 0; r < 4; ++r) {
      int n = (w*4 + at)*16 + hi*4 + r;
      b3v[r]  = b3[n];
      w30v[r] = W3[n];                 // W3 row 0 = dist weights
      w4v[r]  = *reinterpret_cast<const float4*>(&W4[n*4]);
    }
    #pragma unroll
    for (int bt = 0; bt < 4; ++bt) {
      float d = dist_lds[bt*16 + c15];
      #pragma unroll
      for (int r = 0; r < 4; ++r) {
        float z  = acc[at][bt][r] + d*w30v[r] + b3v[r];
        float rz = fmaxf(z, 0.f);
        pe[bt].x += rz*w4v[r].x; pe[bt].y += rz*w4v[r].y;
        pe[bt].z += rz*w4v[r].z; pe[bt].w += rz*w4v[r].w;
      }
    }
  }
  #pragma unroll
  for (int bt = 0; bt < 4; ++bt) {
    int pair = bt*16 + c15;
    float4 p = pe[bt];
    p.x += __shfl_xor(p.x, 16); p.y += __shfl_xor(p.y, 16);
    p.z += __shfl_xor(p.z, 16); p.w += __shfl_xor(p.w, 16);
    p.x += __shfl_xor(p.x, 32); p.y += __shfl_xor(p.y, 32);
    p.z += __shfl_xor(p.z, 32); p.w += __shfl_xor(p.w, 32);
    if (hi == 0) *reinterpret_cast<float4*>(&partial[w][pair][0]) = p;
  }
  __syncthreads();
  if (tid < 64) {
    int pair = tid;
    float4 v;
    v.x = partial[0][pair][0] + partial[1][pair][0] + partial[2][pair][0] + partial[3][pair][0];
    v.y = partial[0][pair][1] + partial[1][pair][1] + partial[2][pair][1] + partial[3][pair][1];
    v.z = partial[0][pair][2] + partial[1][pair][2] + partial[2][pair][2] + partial[3][pair][2];
    v.w = partial[0][pair][3] + partial[1][pair][3] + partial[2][pair][3] + partial[3][pair][3];
    const float4 bv = *reinterpret_cast<const float4*>(b4);
    v.x += bv.x; v.y += bv.y; v.z += bv.z; v.w += bv.w;
    int il = it*16 + qq4*4 + (pair >> 4);   // local i row
    int jl = jt*16 + (pair & 15);           // local j row
    *reinterpret_cast<float4*>(&out[(((size_t)b*256 + il)*256 + jl)*NE]) = v;
    if (it != jt)
      *reinterpret_cast<float4*>(&out[(((size_t)b*256 + jl)*256 + il)*NE]) = v;
  }
}

extern "C" void kernel_launch(void* const* d_in, const int* in_sizes, int n_in,
                              void* d_out, int out_size, void* d_ws, size_t ws_size,
                              hipStream_t stream) {
  const float* latent    = (const float*)d_in[0];
  const float* positions = (const float*)d_in[1];
  const float* atoms     = (const float*)d_in[2];
  const float* W1 = (const float*)d_in[3];
  const float* b1 = (const float*)d_in[4];
  const float* W2 = (const float*)d_in[5];
  const float* b2 = (const float*)d_in[6];
  const float* W3 = (const float*)d_in[7];
  const float* b3 = (const float*)d_in[8];
  const float* W4 = (const float*)d_in[9];
  const float* b4 = (const float*)d_in[10];
  float* out = (float*)d_out;

  char* ws = (char*)d_ws;
  ushort* Gf_ws   = (ushort*)ws;                        // 8*256*288*2 = 1,179,648 B
  ushort* W3Tf_ws = (ushort*)(ws + 1179648);            // 256*288*2   =   147,456 B

  hipLaunchKernelGGL(prep_h_kernel, dim3(256), dim3(256), 0, stream,
                     latent, atoms, W1, b1, W2, b2, Gf_ws);
  hipLaunchKernelGGL(prep_w3t_kernel, dim3(256), dim3(256), 0, stream, W3, W3Tf_ws);
  hipLaunchKernelGGL(edge_main_kernel, dim3(4352), dim3(256), 0, stream,
                     positions, W3, b3, W4, b4, Gf_ws, W3Tf_ws, out);
}

// Round 22
// 115.094 us; speedup vs baseline: 1.0046x; 1.0028x over previous
//
#include <hip/hip_runtime.h>

#define DIM 256
#define NA 16
#define NE 4
#define KTOT 288   // 16 atoms + 256 latent + 16 zero pad (9 chunks of 32)

typedef __attribute__((ext_vector_type(8))) short short8;
typedef __attribute__((ext_vector_type(4))) float f32x4;

static __device__ __forceinline__ ushort f2bf(float f) {
  union { float f; unsigned int u; } v; v.f = f;
  unsigned int r = (v.u + 0x7FFFu + ((v.u >> 16) & 1u)) >> 16;
  return (ushort)r;
}

static __device__ __forceinline__ float bf2f(ushort s) {
  union { unsigned int u; float f; } v; v.u = ((unsigned int)s) << 16;
  return v.f;
}

static __device__ __forceinline__ unsigned cvtpk(float lo, float hi) {
  unsigned r;
  asm("v_cvt_pk_bf16_f32 %0, %1, %2" : "=v"(r) : "v"(lo), "v"(hi));
  return r;
}

// fragment-major index (ushort units): subtile = 16 rows x 32 cols = 1KB,
// laid out [row-block rb][k-chunk kk][oct][r15][e]:
//   idx = ((rb*9 + kk)*4 + oct)*128 + r15*8 + e
static __device__ __forceinline__ int fragIdx(int row, int c) {
  return (((row >> 4)*9 + (c >> 5))*4 + ((c >> 3) & 3))*128 + (row & 15)*8 + (c & 7);
}

// ---------------- prep 1: h = relu(latent@W1+b1)@W2+b2 ; Gf = frag-major [atoms|h|0] bf16
__global__ __launch_bounds__(256) void prep_h_kernel(
    const float* __restrict__ latent, const float* __restrict__ atoms,
    const float* __restrict__ W1, const float* __restrict__ b1,
    const float* __restrict__ W2, const float* __restrict__ b2,
    ushort* __restrict__ Gf) {
  __shared__ float lat[8][DIM];
  __shared__ float t1[8][DIM];
  const int b = blockIdx.x >> 5, i0 = (blockIdx.x & 31) * 8;
  const int k = threadIdx.x;
  #pragma unroll
  for (int r = 0; r < 8; ++r) lat[r][k] = latent[(b*256 + i0 + r) * DIM + k];
  __syncthreads();
  float acc[8];
  #pragma unroll
  for (int r = 0; r < 8; ++r) acc[r] = b1[k];
  for (int c = 0; c < DIM; c += 4) {
    float w0 = W1[(c+0)*DIM + k], w1 = W1[(c+1)*DIM + k];
    float w2 = W1[(c+2)*DIM + k], w3 = W1[(c+3)*DIM + k];
    #pragma unroll
    for (int r = 0; r < 8; ++r) {
      const float4 l4 = *reinterpret_cast<const float4*>(&lat[r][c]);
      acc[r] += l4.x*w0 + l4.y*w1 + l4.z*w2 + l4.w*w3;
    }
  }
  #pragma unroll
  for (int r = 0; r < 8; ++r) t1[r][k] = fmaxf(acc[r], 0.f);
  __syncthreads();
  #pragma unroll
  for (int r = 0; r < 8; ++r) acc[r] = b2[k];
  for (int c = 0; c < DIM; c += 4) {
    float w0 = W2[(c+0)*DIM + k], w1 = W2[(c+1)*DIM + k];
    float w2 = W2[(c+2)*DIM + k], w3 = W2[(c+3)*DIM + k];
    #pragma unroll
    for (int r = 0; r < 8; ++r) {
      const float4 l4 = *reinterpret_cast<const float4*>(&t1[r][c]);
      acc[r] += l4.x*w0 + l4.y*w1 + l4.z*w2 + l4.w*w3;
    }
  }
  #pragma unroll
  for (int r = 0; r < 8; ++r) {
    int row = b*256 + i0 + r;
    Gf[fragIdx(row, NA + k)] = f2bf(acc[r]);
  }
  if (k < NA) {
    #pragma unroll
    for (int r = 0; r < 8; ++r) {
      int row = b*256 + i0 + r;
      Gf[fragIdx(row, k)] = f2bf(atoms[row*NA + k]);
      Gf[fragIdx(row, 272 + k)] = 0;
    }
  }
}

// ---------------- prep 2: W3Tf frag-major: value(n,c) = bf16(W3[1+c][n]), pad 0
__global__ __launch_bounds__(256) void prep_w3t_kernel(
    const float* __restrict__ W3, ushort* __restrict__ W3Tf) {
  const int n = blockIdx.x, c = threadIdx.x;
  W3Tf[fragIdx(n, c)] = (c < 272) ? f2bf(W3[(1+c)*DIM + n]) : (ushort)0;
  if (c < 32) {
    int c2 = 256 + c;
    W3Tf[fragIdx(n, c2)] = (c2 < 272) ? f2bf(W3[(1+c2)*DIM + n]) : (ushort)0;
  }
}

// ---------------- main: one WG per (b, it<=jt, i-quarter) = 4352 WGs x 256 thr.
// Cooperative y-build + K-loop with PINNED 1-deep afr pipeline:
//   issue af[nxt] (L2) + bbv ds_reads, then sched_barrier(0), then MFMA.
// The fence stops hipcc from sinking the prefetch (R21: VGPR=84 proved it sank).
// vmcnt-wait for af[nxt] lands one full MFMA cluster later (~240 SIMD-cyc).
__global__ __attribute__((amdgpu_flat_work_group_size(256,256), amdgpu_waves_per_eu(3,3)))
void edge_main_kernel(
    const float* __restrict__ positions,
    const float* __restrict__ W3, const float* __restrict__ b3,
    const float* __restrict__ W4, const float* __restrict__ b4,
    const ushort* __restrict__ Gf, const ushort* __restrict__ W3Tf,
    float* __restrict__ out) {
  __shared__ ushort y_lds[9*64*5*8];     // y[kk][pair][slot5] 8-elem octets, 45KB
  __shared__ float partial[4][64][4];    // 4KB
  __shared__ float dist_lds[64];

  const int bid = blockIdx.x;
  const int b = bid / 544;               // 136 tiles * 4 quarters per b
  int rem = bid - b*544;
  const int qq4 = rem & 3;               // i-quarter: rows [qq4*4, qq4*4+4)
  int q = rem >> 2;
  int it = 0;
  while (q >= 16 - it) { q -= 16 - it; ++it; }
  const int jt = it + q;
  const int i0 = b*256 + it*16, j0 = b*256 + jt*16;
  const int rbi = i0 >> 4, rbj = j0 >> 4;

  const int tid = threadIdx.x;
  const int lane = tid & 63, w = tid >> 6;   // w = n-group (ntiles w*4..+4)
  const int c15 = lane & 15, hi = lane >> 4;

  // ---- cooperative y-build: thread (p = tid>>2, oct = tid&3) computes
  // y[kk][p][oct] = bf16(gi[qq4*4 + p>>4][kk*32+oct*8..+8] * gj[p&15][same])
  {
    const int p = tid >> 2, oct = tid & 3;
    const int ri = qq4*4 + (p >> 4);         // i-row within block (0..15)
    const int rj = p & 15;                   // j-row within block
    const ushort* giB = &Gf[(size_t)(rbi*9)*512 + oct*128 + ri*8];
    const ushort* gjB = &Gf[(size_t)(rbj*9)*512 + oct*128 + rj*8];
    #pragma unroll
    for (int kk = 0; kk < 9; ++kk) {
      union { ushort us[8]; short8 s8; } gi, gj;
      gi.s8 = *reinterpret_cast<const short8*>(giB + kk*512);
      gj.s8 = *reinterpret_cast<const short8*>(gjB + kk*512);
      union { unsigned uu[4]; short8 s8; } pk;
      pk.uu[0] = cvtpk(bf2f(gi.us[0])*bf2f(gj.us[0]), bf2f(gi.us[1])*bf2f(gj.us[1]));
      pk.uu[1] = cvtpk(bf2f(gi.us[2])*bf2f(gj.us[2]), bf2f(gi.us[3])*bf2f(gj.us[3]));
      pk.uu[2] = cvtpk(bf2f(gi.us[4])*bf2f(gj.us[4]), bf2f(gi.us[5])*bf2f(gj.us[5]));
      pk.uu[3] = cvtpk(bf2f(gi.us[6])*bf2f(gj.us[6]), bf2f(gi.us[7])*bf2f(gj.us[7]));
      *reinterpret_cast<short8*>(&y_lds[((kk*64 + p)*5 + oct)*8]) = pk.s8;
    }
  }
  if (tid < 64) {
    int pi = tid >> 4, pj = tid & 15;
    const float* pa = &positions[(i0 + qq4*4 + pi)*3];
    const float* pb = &positions[(j0 + pj)*3];
    float dx = pa[0]-pb[0], dy = pa[1]-pb[1], dz = pa[2]-pb[2];
    float d2 = dx*dx + dy*dy + dz*dz;
    dist_lds[tid] = d2 > 0.f ? sqrtf(d2) : 0.f;
  }

  f32x4 acc[4][4];
  #pragma unroll
  for (int at = 0; at < 4; ++at)
    #pragma unroll
    for (int bt = 0; bt < 4; ++bt) { acc[at][bt].x=0.f; acc[at][bt].y=0.f; acc[at][bt].z=0.f; acc[at][bt].w=0.f; }

  __syncthreads();   // y + dist visible; no more barriers until epilogue

  // ---- K-loop with pinned ping-pong afr pipeline
  short8 af[2][4];
  #pragma unroll
  for (int at = 0; at < 4; ++at)
    af[0][at] = *reinterpret_cast<const short8*>(&W3Tf[((w*4 + at)*9 + 0)*512 + lane*8]);

  #pragma unroll
  for (int kk = 0; kk < 9; ++kk) {
    const int cur = kk & 1, nxt = cur ^ 1;
    if (kk < 8) {
      #pragma unroll
      for (int at = 0; at < 4; ++at)
        af[nxt][at] = *reinterpret_cast<const short8*>(
            &W3Tf[((w*4 + at)*9 + (kk+1))*512 + lane*8]);
    }
    short8 bbv[4];
    #pragma unroll
    for (int bt = 0; bt < 4; ++bt)
      bbv[bt] = *reinterpret_cast<const short8*>(
          &y_lds[((kk*64 + bt*16 + c15)*5 + hi)*8]);
    __builtin_amdgcn_sched_barrier(0);   // pin: loads above, MFMAs below
    #pragma unroll
    for (int at = 0; at < 4; ++at) {
      acc[at][0] = __builtin_amdgcn_mfma_f32_16x16x32_bf16(af[cur][at], bbv[0], acc[at][0], 0, 0, 0);
      acc[at][1] = __builtin_amdgcn_mfma_f32_16x16x32_bf16(af[cur][at], bbv[1], acc[at][1], 0, 0, 0);
      acc[at][2] = __builtin_amdgcn_mfma_f32_16x16x32_bf16(af[cur][at], bbv[2], acc[at][2], 0, 0, 0);
      acc[at][3] = __builtin_amdgcn_mfma_f32_16x16x32_bf16(af[cur][at], bbv[3], acc[at][3], 0, 0, 0);
    }
  }

  __builtin_amdgcn_sched_barrier(0);   // keep epilogue loads out of K-loop region

  // ---- epilogue: per-at constant loading caps register pressure
  float4 pe[4];
  #pragma unroll
  for (int bt = 0; bt < 4; ++bt) { pe[bt].x=0.f; pe[bt].y=0.f; pe[bt].z=0.f; pe[bt].w=0.f; }
  #pragma unroll
  for (int at = 0; at < 4; ++at) {
    float b3v[4], w30v[4]; float4 w4v[4];
    #pragma unroll
    for (int r = 0; r < 4; ++r) {
      int n = (w*4 + at)*16 + hi*4 + r;
      b3v[r]  = b3[n];
      w30v[r] = W3[n];                 // W3 row 0 = dist weights
      w4v[r]  = *reinterpret_cast<const float4*>(&W4[n*4]);
    }
    #pragma unroll
    for (int bt = 0; bt < 4; ++bt) {
      float d = dist_lds[bt*16 + c15];
      #pragma unroll
      for (int r = 0; r < 4; ++r) {
        float z  = acc[at][bt][r] + d*w30v[r] + b3v[r];
        float rz = fmaxf(z, 0.f);
        pe[bt].x += rz*w4v[r].x; pe[bt].y += rz*w4v[r].y;
        pe[bt].z += rz*w4v[r].z; pe[bt].w += rz*w4v[r].w;
      }
    }
  }
  #pragma unroll
  for (int bt = 0; bt < 4; ++bt) {
    int pair = bt*16 + c15;
    float4 p = pe[bt];
    p.x += __shfl_xor(p.x, 16); p.y += __shfl_xor(p.y, 16);
    p.z += __shfl_xor(p.z, 16); p.w += __shfl_xor(p.w, 16);
    p.x += __shfl_xor(p.x, 32); p.y += __shfl_xor(p.y, 32);
    p.z += __shfl_xor(p.z, 32); p.w += __shfl_xor(p.w, 32);
    if (hi == 0) *reinterpret_cast<float4*>(&partial[w][pair][0]) = p;
  }
  __syncthreads();
  if (tid < 64) {
    int pair = tid;
    float4 v;
    v.x = partial[0][pair][0] + partial[1][pair][0] + partial[2][pair][0] + partial[3][pair][0];
    v.y = partial[0][pair][1] + partial[1][pair][1] + partial[2][pair][1] + partial[3][pair][1];
    v.z = partial[0][pair][2] + partial[1][pair][2] + partial[2][pair][2] + partial[3][pair][2];
    v.w = partial[0][pair][3] + partial[1][pair][3] + partial[2][pair][3] + partial[3][pair][3];
    const float4 bv = *reinterpret_cast<const float4*>(b4);
    v.x += bv.x; v.y += bv.y; v.z += bv.z; v.w += bv.w;
    int il = it*16 + qq4*4 + (pair >> 4);   // local i row
    int jl = jt*16 + (pair & 15);           // local j row
    *reinterpret_cast<float4*>(&out[(((size_t)b*256 + il)*256 + jl)*NE]) = v;
    if (it != jt)
      *reinterpret_cast<float4*>(&out[(((size_t)b*256 + jl)*256 + il)*NE]) = v;
  }
}

extern "C" void kernel_launch(void* const* d_in, const int* in_sizes, int n_in,
                              void* d_out, int out_size, void* d_ws, size_t ws_size,
                              hipStream_t stream) {
  const float* latent    = (const float*)d_in[0];
  const float* positions = (const float*)d_in[1];
  const float* atoms     = (const float*)d_in[2];
  const float* W1 = (const float*)d_in[3];
  const float* b1 = (const float*)d_in[4];
  const float* W2 = (const float*)d_in[5];
  const float* b2 = (const float*)d_in[6];
  const float* W3 = (const float*)d_in[7];
  const float* b3 = (const float*)d_in[8];
  const float* W4 = (const float*)d_in[9];
  const float* b4 = (const float*)d_in[10];
  float* out = (float*)d_out;

  char* ws = (char*)d_ws;
  ushort* Gf_ws   = (ushort*)ws;                        // 8*256*288*2 = 1,179,648 B
  ushort* W3Tf_ws = (ushort*)(ws + 1179648);            // 256*288*2   =   147,456 B

  hipLaunchKernelGGL(prep_h_kernel, dim3(256), dim3(256), 0, stream,
                     latent, atoms, W1, b1, W2, b2, Gf_ws);
  hipLaunchKernelGGL(prep_w3t_kernel, dim3(256), dim3(256), 0, stream, W3, W3Tf_ws);
  hipLaunchKernelGGL(edge_main_kernel, dim3(4352), dim3(256), 0, stream,
                     positions, W3, b3, W4, b4, Gf_ws, W3Tf_ws, out);
}

// Round 23
// 97.370 us; speedup vs baseline: 1.1875x; 1.1820x over previous
//
#include <hip/hip_runtime.h>

#define DIM 256
#define NA 16
#define NE 4
#define KTOT 288   // 16 atoms + 256 latent + 16 zero pad (9 chunks of 32)

typedef __attribute__((ext_vector_type(8))) short short8;
typedef __attribute__((ext_vector_type(4))) float f32x4;

static __device__ __forceinline__ ushort f2bf(float f) {
  union { float f; unsigned int u; } v; v.f = f;
  unsigned int r = (v.u + 0x7FFFu + ((v.u >> 16) & 1u)) >> 16;
  return (ushort)r;
}

static __device__ __forceinline__ float bf2f(ushort s) {
  union { unsigned int u; float f; } v; v.u = ((unsigned int)s) << 16;
  return v.f;
}

static __device__ __forceinline__ unsigned cvtpk(float lo, float hi) {
  unsigned r;
  asm("v_cvt_pk_bf16_f32 %0, %1, %2" : "=v"(r) : "v"(lo), "v"(hi));
  return r;
}

// fragment-major index (ushort units): subtile = 16 rows x 32 cols = 1KB,
// laid out [row-block rb][k-chunk kk][oct][r15][e]:
//   idx = ((rb*9 + kk)*4 + oct)*128 + r15*8 + e
static __device__ __forceinline__ int fragIdx(int row, int c) {
  return (((row >> 4)*9 + (c >> 5))*4 + ((c >> 3) & 3))*128 + (row & 15)*8 + (c & 7);
}

// ---------------- fused prep: WGs 0..511 -> h/Gf (4 rows each, 2 WG/CU);
//                  WGs 512..767 -> W3Tf transpose. Run concurrently.
__global__ __launch_bounds__(256) void prep_kernel(
    const float* __restrict__ latent, const float* __restrict__ atoms,
    const float* __restrict__ W1, const float* __restrict__ b1,
    const float* __restrict__ W2, const float* __restrict__ b2,
    const float* __restrict__ W3,
    ushort* __restrict__ Gf, ushort* __restrict__ W3Tf) {
  __shared__ float lat[4][DIM];
  __shared__ float t1[4][DIM];
  const int k = threadIdx.x;

  if (blockIdx.x >= 512) {           // ---- W3Tf part
    const int n = blockIdx.x - 512;
    W3Tf[fragIdx(n, k)] = (k < 272) ? f2bf(W3[(1+k)*DIM + n]) : (ushort)0;
    if (k < 32) {
      int c2 = 256 + k;
      W3Tf[fragIdx(n, c2)] = (c2 < 272) ? f2bf(W3[(1+c2)*DIM + n]) : (ushort)0;
    }
    return;
  }

  // ---- h part: 4 rows per WG
  const int b = blockIdx.x >> 6, i0 = (blockIdx.x & 63) * 4;
  #pragma unroll
  for (int r = 0; r < 4; ++r) lat[r][k] = latent[(b*256 + i0 + r) * DIM + k];
  __syncthreads();
  float acc[4];
  #pragma unroll
  for (int r = 0; r < 4; ++r) acc[r] = b1[k];
  for (int c = 0; c < DIM; c += 4) {
    float w0 = W1[(c+0)*DIM + k], w1 = W1[(c+1)*DIM + k];
    float w2 = W1[(c+2)*DIM + k], w3 = W1[(c+3)*DIM + k];
    #pragma unroll
    for (int r = 0; r < 4; ++r) {
      const float4 l4 = *reinterpret_cast<const float4*>(&lat[r][c]);
      acc[r] += l4.x*w0 + l4.y*w1 + l4.z*w2 + l4.w*w3;
    }
  }
  #pragma unroll
  for (int r = 0; r < 4; ++r) t1[r][k] = fmaxf(acc[r], 0.f);
  __syncthreads();
  #pragma unroll
  for (int r = 0; r < 4; ++r) acc[r] = b2[k];
  for (int c = 0; c < DIM; c += 4) {
    float w0 = W2[(c+0)*DIM + k], w1 = W2[(c+1)*DIM + k];
    float w2 = W2[(c+2)*DIM + k], w3 = W2[(c+3)*DIM + k];
    #pragma unroll
    for (int r = 0; r < 4; ++r) {
      const float4 l4 = *reinterpret_cast<const float4*>(&t1[r][c]);
      acc[r] += l4.x*w0 + l4.y*w1 + l4.z*w2 + l4.w*w3;
    }
  }
  #pragma unroll
  for (int r = 0; r < 4; ++r) {
    int row = b*256 + i0 + r;
    Gf[fragIdx(row, NA + k)] = f2bf(acc[r]);
  }
  if (k < NA) {
    #pragma unroll
    for (int r = 0; r < 4; ++r) {
      int row = b*256 + i0 + r;
      Gf[fragIdx(row, k)] = f2bf(atoms[row*NA + k]);
      Gf[fragIdx(row, 272 + k)] = 0;
    }
  }
}

// ---------------- main: one WG per (b, it<=jt, i-quarter) = 4352 WGs x 256 thr.
// R19 structure (best measured: 82.4us): 4-wave WG, waves_per_eu(3,3) -> 3
// independent WGs/SIMD; per-wave bb-build (the VALU doubles as latency cover);
// gi/gj staged in LDS once; barrier-free K-loop; afr from L2.
// Added: s_setprio around MFMA cluster (T5; WGs are phase-independent here).
__global__ __attribute__((amdgpu_flat_work_group_size(256,256), amdgpu_waves_per_eu(3,3)))
void edge_main_kernel(
    const float* __restrict__ positions,
    const float* __restrict__ W3, const float* __restrict__ b3,
    const float* __restrict__ W4, const float* __restrict__ b4,
    const ushort* __restrict__ Gf, const ushort* __restrict__ W3Tf,
    float* __restrict__ out) {
  __shared__ ushort gi_lds[4608];        // i row-block, frag-major (9.2KB)
  __shared__ ushort gj_lds[4608];        // j row-block, frag-major (9.2KB)
  __shared__ float partial[4][64][4];    // 4KB
  __shared__ float dist_lds[64];

  const int bid = blockIdx.x;
  const int b = bid / 544;               // 136 tiles * 4 quarters per b
  int rem = bid - b*544;
  const int qq4 = rem & 3;               // i-quarter: rows [qq4*4, qq4*4+4)
  int q = rem >> 2;
  int it = 0;
  while (q >= 16 - it) { q -= 16 - it; ++it; }
  const int jt = it + q;
  const int i0 = b*256 + it*16, j0 = b*256 + jt*16;
  const int rbi = i0 >> 4, rbj = j0 >> 4;

  const int tid = threadIdx.x;
  const int lane = tid & 63, w = tid >> 6;   // w = n-group (ntiles w*4..+4)
  const int c15 = lane & 15, hi = lane >> 4;

  // ---- stage the two G row-blocks into LDS (contiguous 9216B each)
  {
    const uint4* srcI = reinterpret_cast<const uint4*>(Gf + (size_t)rbi*4608);
    const uint4* srcJ = reinterpret_cast<const uint4*>(Gf + (size_t)rbj*4608);
    uint4* dI = reinterpret_cast<uint4*>(gi_lds);
    uint4* dJ = reinterpret_cast<uint4*>(gj_lds);
    dI[tid] = srcI[tid];
    dJ[tid] = srcJ[tid];
    dI[256+tid] = srcI[256+tid];
    dJ[256+tid] = srcJ[256+tid];
    if (tid < 64) { dI[512+tid] = srcI[512+tid]; dJ[512+tid] = srcJ[512+tid]; }
  }
  if (tid < 64) {
    int pi = tid >> 4, pj = tid & 15;
    const float* pa = &positions[(i0 + qq4*4 + pi)*3];
    const float* pb = &positions[(j0 + pj)*3];
    float dx = pa[0]-pb[0], dy = pa[1]-pb[1], dz = pa[2]-pb[2];
    float d2 = dx*dx + dy*dy + dz*dz;
    dist_lds[tid] = d2 > 0.f ? sqrtf(d2) : 0.f;
  }

  f32x4 acc[4][4];
  #pragma unroll
  for (int at = 0; at < 4; ++at)
    #pragma unroll
    for (int bt = 0; bt < 4; ++bt) { acc[at][bt].x=0.f; acc[at][bt].y=0.f; acc[at][bt].z=0.f; acc[at][bt].w=0.f; }

  __syncthreads();   // g blocks + dist visible; no more barriers until epilogue

  #pragma unroll
  for (int kk = 0; kk < 9; ++kk) {
    // gj: this lane's j-row octet from LDS (contiguous 1KB per wave)
    union { ushort us[8]; short8 s8; } gj;
    gj.s8 = *reinterpret_cast<const short8*>(&gj_lds[kk*512 + lane*8]);
    float gjf[8];
    #pragma unroll
    for (int s = 0; s < 8; ++s) gjf[s] = bf2f(gj.us[s]);
    // build all 4 B-fragments (bb persists across the at loop; never rebuilt)
    short8 bbv[4];
    #pragma unroll
    for (int bt = 0; bt < 4; ++bt) {
      union { ushort us[8]; short8 s8; } gi;
      gi.s8 = *reinterpret_cast<const short8*>(
          &gi_lds[kk*512 + hi*128 + (qq4*4 + bt)*8]);
      union { unsigned uu[4]; short8 s8; } bb;
      bb.uu[0] = cvtpk(bf2f(gi.us[0])*gjf[0], bf2f(gi.us[1])*gjf[1]);
      bb.uu[1] = cvtpk(bf2f(gi.us[2])*gjf[2], bf2f(gi.us[3])*gjf[3]);
      bb.uu[2] = cvtpk(bf2f(gi.us[4])*gjf[4], bf2f(gi.us[5])*gjf[5]);
      bb.uu[3] = cvtpk(bf2f(gi.us[6])*gjf[6], bf2f(gi.us[7])*gjf[7]);
      bbv[bt] = bb.s8;
    }
    // A-fragments from W3Tf (L2), one at a time (register-lean)
    __builtin_amdgcn_s_setprio(1);
    #pragma unroll
    for (int at = 0; at < 4; ++at) {
      short8 af = *reinterpret_cast<const short8*>(
          &W3Tf[((w*4 + at)*9 + kk)*512 + lane*8]);
      acc[at][0] = __builtin_amdgcn_mfma_f32_16x16x32_bf16(af, bbv[0], acc[at][0], 0, 0, 0);
      acc[at][1] = __builtin_amdgcn_mfma_f32_16x16x32_bf16(af, bbv[1], acc[at][1], 0, 0, 0);
      acc[at][2] = __builtin_amdgcn_mfma_f32_16x16x32_bf16(af, bbv[2], acc[at][2], 0, 0, 0);
      acc[at][3] = __builtin_amdgcn_mfma_f32_16x16x32_bf16(af, bbv[3], acc[at][3], 0, 0, 0);
    }
    __builtin_amdgcn_s_setprio(0);
  }

  __builtin_amdgcn_sched_barrier(0);   // keep epilogue loads out of K-loop region

  // ---- epilogue: per-at constant loading caps register pressure
  float4 pe[4];
  #pragma unroll
  for (int bt = 0; bt < 4; ++bt) { pe[bt].x=0.f; pe[bt].y=0.f; pe[bt].z=0.f; pe[bt].w=0.f; }
  #pragma unroll
  for (int at = 0; at < 4; ++at) {
    float b3v[4], w30v[4]; float4 w4v[4];
    #pragma unroll
    for (int r = 0; r < 4; ++r) {
      int n = (w*4 + at)*16 + hi*4 + r;
      b3v[r]  = b3[n];
      w30v[r] = W3[n];                 // W3 row 0 = dist weights
      w4v[r]  = *reinterpret_cast<const float4*>(&W4[n*4]);
    }
    #pragma unroll
    for (int bt = 0; bt < 4; ++bt) {
      float d = dist_lds[bt*16 + c15];
      #pragma unroll
      for (int r = 0; r < 4; ++r) {
        float z  = acc[at][bt][r] + d*w30v[r] + b3v[r];
        float rz = fmaxf(z, 0.f);
        pe[bt].x += rz*w4v[r].x; pe[bt].y += rz*w4v[r].y;
        pe[bt].z += rz*w4v[r].z; pe[bt].w += rz*w4v[r].w;
      }
    }
  }
  #pragma unroll
  for (int bt = 0; bt < 4; ++bt) {
    int pair = bt*16 + c15;
    float4 p = pe[bt];
    p.x += __shfl_xor(p.x, 16); p.y += __shfl_xor(p.y, 16);
    p.z += __shfl_xor(p.z, 16); p.w += __shfl_xor(p.w, 16);
    p.x += __shfl_xor(p.x, 32); p.y += __shfl_xor(p.y, 32);
    p.z += __shfl_xor(p.z, 32); p.w += __shfl_xor(p.w, 32);
    if (hi == 0) *reinterpret_cast<float4*>(&partial[w][pair][0]) = p;
  }
  __syncthreads();
  if (tid < 64) {
    int pair = tid;
    float4 v;
    v.x = partial[0][pair][0] + partial[1][pair][0] + partial[2][pair][0] + partial[3][pair][0];
    v.y = partial[0][pair][1] + partial[1][pair][1] + partial[2][pair][1] + partial[3][pair][1];
    v.z = partial[0][pair][2] + partial[1][pair][2] + partial[2][pair][2] + partial[3][pair][2];
    v.w = partial[0][pair][3] + partial[1][pair][3] + partial[2][pair][3] + partial[3][pair][3];
    const float4 bv = *reinterpret_cast<const float4*>(b4);
    v.x += bv.x; v.y += bv.y; v.z += bv.z; v.w += bv.w;
    int il = it*16 + qq4*4 + (pair >> 4);   // local i row
    int jl = jt*16 + (pair & 15);           // local j row
    *reinterpret_cast<float4*>(&out[(((size_t)b*256 + il)*256 + jl)*NE]) = v;
    if (it != jt)
      *reinterpret_cast<float4*>(&out[(((size_t)b*256 + jl)*256 + il)*NE]) = v;
  }
}

extern "C" void kernel_launch(void* const* d_in, const int* in_sizes, int n_in,
                              void* d_out, int out_size, void* d_ws, size_t ws_size,
                              hipStream_t stream) {
  const float* latent    = (const float*)d_in[0];
  const float* positions = (const float*)d_in[1];
  const float* atoms     = (const float*)d_in[2];
  const float* W1 = (const float*)d_in[3];
  const float* b1 = (const float*)d_in[4];
  const float* W2 = (const float*)d_in[5];
  const float* b2 = (const float*)d_in[6];
  const float* W3 = (const float*)d_in[7];
  const float* b3 = (const float*)d_in[8];
  const float* W4 = (const float*)d_in[9];
  const float* b4 = (const float*)d_in[10];
  float* out = (float*)d_out;

  char* ws = (char*)d_ws;
  ushort* Gf_ws   = (ushort*)ws;                        // 8*256*288*2 = 1,179,648 B
  ushort* W3Tf_ws = (ushort*)(ws + 1179648);            // 256*288*2   =   147,456 B

  hipLaunchKernelGGL(prep_kernel, dim3(768), dim3(256), 0, stream,
                     latent, atoms, W1, b1, W2, b2, W3, Gf_ws, W3Tf_ws);
  hipLaunchKernelGGL(edge_main_kernel, dim3(4352), dim3(256), 0, stream,
                     positions, W3, b3, W4, b4, Gf_ws, W3Tf_ws, out);
}

// Round 24
// 93.185 us; speedup vs baseline: 1.2408x; 1.0449x over previous
//
#include <hip/hip_runtime.h>

#define DIM 256
#define NA 16
#define NE 4
#define KTOT 288   // 16 atoms + 256 latent + 16 zero pad (9 chunks of 32)

typedef __attribute__((ext_vector_type(8))) short short8;
typedef __attribute__((ext_vector_type(4))) float f32x4;

static __device__ __forceinline__ ushort f2bf(float f) {
  union { float f; unsigned int u; } v; v.f = f;
  unsigned int r = (v.u + 0x7FFFu + ((v.u >> 16) & 1u)) >> 16;
  return (ushort)r;
}

static __device__ __forceinline__ float bf2f(ushort s) {
  union { unsigned int u; float f; } v; v.u = ((unsigned int)s) << 16;
  return v.f;
}

static __device__ __forceinline__ unsigned cvtpk(float lo, float hi) {
  unsigned r;
  asm("v_cvt_pk_bf16_f32 %0, %1, %2" : "=v"(r) : "v"(lo), "v"(hi));
  return r;
}

// fragment-major index (ushort units): subtile = 16 rows x 32 cols = 1KB,
// laid out [row-block rb][k-chunk kk][oct][r15][e]:
//   idx = ((rb*9 + kk)*4 + oct)*128 + r15*8 + e
static __device__ __forceinline__ int fragIdx(int row, int c) {
  return (((row >> 4)*9 + (c >> 5))*4 + ((c >> 3) & 3))*128 + (row & 15)*8 + (c & 7);
}

// ---------------- fused prep: WGs 0..511 -> h/Gf (4 rows each, 2 WG/CU);
//                  WGs 512..767 -> W3Tf transpose. Run concurrently.
__global__ __launch_bounds__(256) void prep_kernel(
    const float* __restrict__ latent, const float* __restrict__ atoms,
    const float* __restrict__ W1, const float* __restrict__ b1,
    const float* __restrict__ W2, const float* __restrict__ b2,
    const float* __restrict__ W3,
    ushort* __restrict__ Gf, ushort* __restrict__ W3Tf) {
  __shared__ float lat[4][DIM];
  __shared__ float t1[4][DIM];
  const int k = threadIdx.x;

  if (blockIdx.x >= 512) {           // ---- W3Tf part
    const int n = blockIdx.x - 512;
    W3Tf[fragIdx(n, k)] = (k < 272) ? f2bf(W3[(1+k)*DIM + n]) : (ushort)0;
    if (k < 32) {
      int c2 = 256 + k;
      W3Tf[fragIdx(n, c2)] = (c2 < 272) ? f2bf(W3[(1+c2)*DIM + n]) : (ushort)0;
    }
    return;
  }

  // ---- h part: 4 rows per WG
  const int b = blockIdx.x >> 6, i0 = (blockIdx.x & 63) * 4;
  #pragma unroll
  for (int r = 0; r < 4; ++r) lat[r][k] = latent[(b*256 + i0 + r) * DIM + k];
  __syncthreads();
  float acc[4];
  #pragma unroll
  for (int r = 0; r < 4; ++r) acc[r] = b1[k];
  for (int c = 0; c < DIM; c += 4) {
    float w0 = W1[(c+0)*DIM + k], w1 = W1[(c+1)*DIM + k];
    float w2 = W1[(c+2)*DIM + k], w3 = W1[(c+3)*DIM + k];
    #pragma unroll
    for (int r = 0; r < 4; ++r) {
      const float4 l4 = *reinterpret_cast<const float4*>(&lat[r][c]);
      acc[r] += l4.x*w0 + l4.y*w1 + l4.z*w2 + l4.w*w3;
    }
  }
  #pragma unroll
  for (int r = 0; r < 4; ++r) t1[r][k] = fmaxf(acc[r], 0.f);
  __syncthreads();
  #pragma unroll
  for (int r = 0; r < 4; ++r) acc[r] = b2[k];
  for (int c = 0; c < DIM; c += 4) {
    float w0 = W2[(c+0)*DIM + k], w1 = W2[(c+1)*DIM + k];
    float w2 = W2[(c+2)*DIM + k], w3 = W2[(c+3)*DIM + k];
    #pragma unroll
    for (int r = 0; r < 4; ++r) {
      const float4 l4 = *reinterpret_cast<const float4*>(&t1[r][c]);
      acc[r] += l4.x*w0 + l4.y*w1 + l4.z*w2 + l4.w*w3;
    }
  }
  #pragma unroll
  for (int r = 0; r < 4; ++r) {
    int row = b*256 + i0 + r;
    Gf[fragIdx(row, NA + k)] = f2bf(acc[r]);
  }
  if (k < NA) {
    #pragma unroll
    for (int r = 0; r < 4; ++r) {
      int row = b*256 + i0 + r;
      Gf[fragIdx(row, k)] = f2bf(atoms[row*NA + k]);
      Gf[fragIdx(row, 272 + k)] = 0;
    }
  }
}

// ---------------- main: one WG per (b, it<=jt, i-quarter) = 4352 WGs x 256 thr.
// R19 structure (best: 82.4us) with afr loads HOISTED to the top of each kk:
// the 4 L2 loads are issued before the bb-build, so the ~176cyc of bb VALU
// (x3 interleaved waves) covers L2 latency; MFMAs find operands ready.
// (R23 lesson: setprio cost ~3us here -> removed.)
__global__ __attribute__((amdgpu_flat_work_group_size(256,256), amdgpu_waves_per_eu(3,3)))
void edge_main_kernel(
    const float* __restrict__ positions,
    const float* __restrict__ W3, const float* __restrict__ b3,
    const float* __restrict__ W4, const float* __restrict__ b4,
    const ushort* __restrict__ Gf, const ushort* __restrict__ W3Tf,
    float* __restrict__ out) {
  __shared__ ushort gi_lds[4608];        // i row-block, frag-major (9.2KB)
  __shared__ ushort gj_lds[4608];        // j row-block, frag-major (9.2KB)
  __shared__ float partial[4][64][4];    // 4KB
  __shared__ float dist_lds[64];

  const int bid = blockIdx.x;
  const int b = bid / 544;               // 136 tiles * 4 quarters per b
  int rem = bid - b*544;
  const int qq4 = rem & 3;               // i-quarter: rows [qq4*4, qq4*4+4)
  int q = rem >> 2;
  int it = 0;
  while (q >= 16 - it) { q -= 16 - it; ++it; }
  const int jt = it + q;
  const int i0 = b*256 + it*16, j0 = b*256 + jt*16;
  const int rbi = i0 >> 4, rbj = j0 >> 4;

  const int tid = threadIdx.x;
  const int lane = tid & 63, w = tid >> 6;   // w = n-group (ntiles w*4..+4)
  const int c15 = lane & 15, hi = lane >> 4;

  // ---- stage the two G row-blocks into LDS (contiguous 9216B each)
  {
    const uint4* srcI = reinterpret_cast<const uint4*>(Gf + (size_t)rbi*4608);
    const uint4* srcJ = reinterpret_cast<const uint4*>(Gf + (size_t)rbj*4608);
    uint4* dI = reinterpret_cast<uint4*>(gi_lds);
    uint4* dJ = reinterpret_cast<uint4*>(gj_lds);
    dI[tid] = srcI[tid];
    dJ[tid] = srcJ[tid];
    dI[256+tid] = srcI[256+tid];
    dJ[256+tid] = srcJ[256+tid];
    if (tid < 64) { dI[512+tid] = srcI[512+tid]; dJ[512+tid] = srcJ[512+tid]; }
  }
  if (tid < 64) {
    int pi = tid >> 4, pj = tid & 15;
    const float* pa = &positions[(i0 + qq4*4 + pi)*3];
    const float* pb = &positions[(j0 + pj)*3];
    float dx = pa[0]-pb[0], dy = pa[1]-pb[1], dz = pa[2]-pb[2];
    float d2 = dx*dx + dy*dy + dz*dz;
    dist_lds[tid] = d2 > 0.f ? sqrtf(d2) : 0.f;
  }

  f32x4 acc[4][4];
  #pragma unroll
  for (int at = 0; at < 4; ++at)
    #pragma unroll
    for (int bt = 0; bt < 4; ++bt) { acc[at][bt].x=0.f; acc[at][bt].y=0.f; acc[at][bt].z=0.f; acc[at][bt].w=0.f; }

  __syncthreads();   // g blocks + dist visible; no more barriers until epilogue

  #pragma unroll
  for (int kk = 0; kk < 9; ++kk) {
    // afr: ALL FOUR A-fragments issued first (L2); bb-build below covers latency
    short8 afv[4];
    #pragma unroll
    for (int at = 0; at < 4; ++at)
      afv[at] = *reinterpret_cast<const short8*>(
          &W3Tf[((w*4 + at)*9 + kk)*512 + lane*8]);
    // gj: this lane's j-row octet from LDS (contiguous 1KB per wave)
    union { ushort us[8]; short8 s8; } gj;
    gj.s8 = *reinterpret_cast<const short8*>(&gj_lds[kk*512 + lane*8]);
    float gjf[8];
    #pragma unroll
    for (int s = 0; s < 8; ++s) gjf[s] = bf2f(gj.us[s]);
    // build all 4 B-fragments (VALU here hides the afr L2 latency)
    short8 bbv[4];
    #pragma unroll
    for (int bt = 0; bt < 4; ++bt) {
      union { ushort us[8]; short8 s8; } gi;
      gi.s8 = *reinterpret_cast<const short8*>(
          &gi_lds[kk*512 + hi*128 + (qq4*4 + bt)*8]);
      union { unsigned uu[4]; short8 s8; } bb;
      bb.uu[0] = cvtpk(bf2f(gi.us[0])*gjf[0], bf2f(gi.us[1])*gjf[1]);
      bb.uu[1] = cvtpk(bf2f(gi.us[2])*gjf[2], bf2f(gi.us[3])*gjf[3]);
      bb.uu[2] = cvtpk(bf2f(gi.us[4])*gjf[4], bf2f(gi.us[5])*gjf[5]);
      bb.uu[3] = cvtpk(bf2f(gi.us[6])*gjf[6], bf2f(gi.us[7])*gjf[7]);
      bbv[bt] = bb.s8;
    }
    #pragma unroll
    for (int at = 0; at < 4; ++at) {
      acc[at][0] = __builtin_amdgcn_mfma_f32_16x16x32_bf16(afv[at], bbv[0], acc[at][0], 0, 0, 0);
      acc[at][1] = __builtin_amdgcn_mfma_f32_16x16x32_bf16(afv[at], bbv[1], acc[at][1], 0, 0, 0);
      acc[at][2] = __builtin_amdgcn_mfma_f32_16x16x32_bf16(afv[at], bbv[2], acc[at][2], 0, 0, 0);
      acc[at][3] = __builtin_amdgcn_mfma_f32_16x16x32_bf16(afv[at], bbv[3], acc[at][3], 0, 0, 0);
    }
  }

  __builtin_amdgcn_sched_barrier(0);   // keep epilogue loads out of K-loop region

  // ---- epilogue: per-at constant loading caps register pressure
  float4 pe[4];
  #pragma unroll
  for (int bt = 0; bt < 4; ++bt) { pe[bt].x=0.f; pe[bt].y=0.f; pe[bt].z=0.f; pe[bt].w=0.f; }
  #pragma unroll
  for (int at = 0; at < 4; ++at) {
    float b3v[4], w30v[4]; float4 w4v[4];
    #pragma unroll
    for (int r = 0; r < 4; ++r) {
      int n = (w*4 + at)*16 + hi*4 + r;
      b3v[r]  = b3[n];
      w30v[r] = W3[n];                 // W3 row 0 = dist weights
      w4v[r]  = *reinterpret_cast<const float4*>(&W4[n*4]);
    }
    #pragma unroll
    for (int bt = 0; bt < 4; ++bt) {
      float d = dist_lds[bt*16 + c15];
      #pragma unroll
      for (int r = 0; r < 4; ++r) {
        float z  = acc[at][bt][r] + d*w30v[r] + b3v[r];
        float rz = fmaxf(z, 0.f);
        pe[bt].x += rz*w4v[r].x; pe[bt].y += rz*w4v[r].y;
        pe[bt].z += rz*w4v[r].z; pe[bt].w += rz*w4v[r].w;
      }
    }
  }
  #pragma unroll
  for (int bt = 0; bt < 4; ++bt) {
    int pair = bt*16 + c15;
    float4 p = pe[bt];
    p.x += __shfl_xor(p.x, 16); p.y += __shfl_xor(p.y, 16);
    p.z += __shfl_xor(p.z, 16); p.w += __shfl_xor(p.w, 16);
    p.x += __shfl_xor(p.x, 32); p.y += __shfl_xor(p.y, 32);
    p.z += __shfl_xor(p.z, 32); p.w += __shfl_xor(p.w, 32);
    if (hi == 0) *reinterpret_cast<float4*>(&partial[w][pair][0]) = p;
  }
  __syncthreads();
  if (tid < 64) {
    int pair = tid;
    float4 v;
    v.x = partial[0][pair][0] + partial[1][pair][0] + partial[2][pair][0] + partial[3][pair][0];
    v.y = partial[0][pair][1] + partial[1][pair][1] + partial[2][pair][1] + partial[3][pair][1];
    v.z = partial[0][pair][2] + partial[1][pair][2] + partial[2][pair][2] + partial[3][pair][2];
    v.w = partial[0][pair][3] + partial[1][pair][3] + partial[2][pair][3] + partial[3][pair][3];
    const float4 bv = *reinterpret_cast<const float4*>(b4);
    v.x += bv.x; v.y += bv.y; v.z += bv.z; v.w += bv.w;
    int il = it*16 + qq4*4 + (pair >> 4);   // local i row
    int jl = jt*16 + (pair & 15);           // local j row
    *reinterpret_cast<float4*>(&out[(((size_t)b*256 + il)*256 + jl)*NE]) = v;
    if (it != jt)
      *reinterpret_cast<float4*>(&out[(((size_t)b*256 + jl)*256 + il)*NE]) = v;
  }
}

extern "C" void kernel_launch(void* const* d_in, const int* in_sizes, int n_in,
                              void* d_out, int out_size, void* d_ws, size_t ws_size,
                              hipStream_t stream) {
  const float* latent    = (const float*)d_in[0];
  const float* positions = (const float*)d_in[1];
  const float* atoms     = (const float*)d_in[2];
  const float* W1 = (const float*)d_in[3];
  const float* b1 = (const float*)d_in[4];
  const float* W2 = (const float*)d_in[5];
  const float* b2 = (const float*)d_in[6];
  const float* W3 = (const float*)d_in[7];
  const float* b3 = (const float*)d_in[8];
  const float* W4 = (const float*)d_in[9];
  const float* b4 = (const float*)d_in[10];
  float* out = (float*)d_out;

  char* ws = (char*)d_ws;
  ushort* Gf_ws   = (ushort*)ws;                        // 8*256*288*2 = 1,179,648 B
  ushort* W3Tf_ws = (ushort*)(ws + 1179648);            // 256*288*2   =   147,456 B

  hipLaunchKernelGGL(prep_kernel, dim3(768), dim3(256), 0, stream,
                     latent, atoms, W1, b1, W2, b2, W3, Gf_ws, W3Tf_ws);
  hipLaunchKernelGGL(edge_main_kernel, dim3(4352), dim3(256), 0, stream,
                     positions, W3, b3, W4, b4, Gf_ws, W3Tf_ws, out);
}